// Round 4
// baseline (431.576 us; speedup 1.0000x reference)
//
#include <hip/hip_runtime.h>

// 4 atoms/thread. Streams (dip, quad, indices, outputs) use non-temporal
// loads/stores so the 48 MB coords array stays L3-resident for the random
// gathers. All gathers are hoisted to the top of the thread (unconditional
// for z/x, predicated for y) so ~30 independent loads overlap their latency.
// NOTE: __builtin_nontemporal_* requires native clang vector types, not
// HIP_vector_type -- use ext_vector_type typedefs.

typedef float f32x4 __attribute__((ext_vector_type(4)));
typedef int   i32x4 __attribute__((ext_vector_type(4)));

__device__ __forceinline__ float3 nrm3(float ax, float ay, float az) {
    float s = ax * ax + ay * ay + az * az;
    float r = 1.0f / sqrtf(s);
    return make_float3(ax * r, ay * r, az * r);
}

// Rotation rows from pre-gathered deltas. dz/dx/dy are (neighbor - self).
__device__ __forceinline__ void rot_from_deltas(
    int t, const float* dz, const float* dx, const float* dy, float R[9])
{
    if (t == 5) {
        R[0] = 1.0f; R[1] = 0.0f; R[2] = 0.0f;
        R[3] = 0.0f; R[4] = 1.0f; R[5] = 0.0f;
        R[6] = 0.0f; R[7] = 0.0f; R[8] = 1.0f;
        return;
    }

    float3 zv = nrm3(dz[0], dz[1], dz[2]);

    float3 xv;
    if (t == 4) {
        xv = make_float3(1.0f - zv.x, zv.x, 0.0f);
    } else {
        xv = nrm3(dx[0], dx[1], dx[2]);
    }

    if (t == 1) {
        zv = nrm3(zv.x + xv.x, zv.y + xv.y, zv.z + xv.z);
    }

    if (t == 2 || t == 3) {
        float3 yn = nrm3(dy[0], dy[1], dy[2]);
        if (t == 2) {
            xv = nrm3(xv.x + yn.x, xv.y + yn.y, xv.z + yn.z);
        } else {
            zv = nrm3(zv.x + xv.x + yn.x, zv.y + xv.y + yn.y, zv.z + xv.z + yn.z);
        }
    }

    float dzx = zv.x * xv.x + zv.y * xv.y + zv.z * xv.z;
    xv = nrm3(xv.x - zv.x * dzx, xv.y - zv.y * dzx, xv.z - zv.z * dzx);

    float3 yv = make_float3(zv.y * xv.z - zv.z * xv.y,
                            zv.z * xv.x - zv.x * xv.z,
                            zv.x * xv.y - zv.y * xv.x);

    R[0] = xv.x; R[1] = xv.y; R[2] = xv.z;
    R[3] = yv.x; R[4] = yv.y; R[5] = yv.z;
    R[6] = zv.x; R[7] = zv.y; R[8] = zv.z;
}

__device__ __forceinline__ void apply_rot(
    const float R[9], const float dp[3], const float Q[9],
    float od[3], float oq[9])
{
    od[0] = dp[0] * R[0] + dp[1] * R[3] + dp[2] * R[6];
    od[1] = dp[0] * R[1] + dp[1] * R[4] + dp[2] * R[7];
    od[2] = dp[0] * R[2] + dp[1] * R[5] + dp[2] * R[8];

    float M[9];
#pragma unroll
    for (int a = 0; a < 3; ++a)
#pragma unroll
        for (int l = 0; l < 3; ++l)
            M[a * 3 + l] = R[0 * 3 + a] * Q[0 * 3 + l]
                         + R[1 * 3 + a] * Q[1 * 3 + l]
                         + R[2 * 3 + a] * Q[2 * 3 + l];
#pragma unroll
    for (int a = 0; a < 3; ++a)
#pragma unroll
        for (int b = 0; b < 3; ++b)
            oq[a * 3 + b] = M[a * 3 + 0] * R[0 * 3 + b]
                          + M[a * 3 + 1] * R[1 * 3 + b]
                          + M[a * 3 + 2] * R[2 * 3 + b];
}

__global__ __launch_bounds__(256) void mp_rot4_nt_kernel(
    const float* __restrict__ coords,
    const int* __restrict__ za,
    const int* __restrict__ xa,
    const int* __restrict__ ya,
    const int* __restrict__ at,
    const float* __restrict__ dip,
    const float* __restrict__ quad,
    float* __restrict__ out_d,
    float* __restrict__ out_q,
    int ngroups, int n)
{
    int g = blockIdx.x * blockDim.x + threadIdx.x;
    if (g >= ngroups) return;
    int base = 4 * g;

    if (base + 4 <= n) {
        // indices / types (read-once streams -> non-temporal)
        i32x4 z4 = __builtin_nontemporal_load((const i32x4*)za + g);
        i32x4 x4 = __builtin_nontemporal_load((const i32x4*)xa + g);
        i32x4 y4 = __builtin_nontemporal_load((const i32x4*)ya + g);
        i32x4 t4 = __builtin_nontemporal_load((const i32x4*)at + g);
        int zi[4] = {z4.x, z4.y, z4.z, z4.w};
        int xi[4] = {x4.x, x4.y, x4.z, x4.w};
        int yi[4] = {y4.x, y4.y, y4.z, y4.w};
        int ti[4] = {t4.x, t4.y, t4.z, t4.w};

        // self coords (temporal -- these lines are also gather targets)
        f32x4 cA = ((const f32x4*)coords)[3 * g + 0];
        f32x4 cB = ((const f32x4*)coords)[3 * g + 1];
        f32x4 cC = ((const f32x4*)coords)[3 * g + 2];
        float c[12] = {cA.x, cA.y, cA.z, cA.w, cB.x, cB.y, cB.z, cB.w,
                       cC.x, cC.y, cC.z, cC.w};

        // ---- hoisted gathers: issue everything before any math ----
        float gz[12], gx[12], gy[12];
#pragma unroll
        for (int a = 0; a < 4; ++a) {
#pragma unroll
            for (int k = 0; k < 3; ++k)
                gz[3 * a + k] = coords[3 * zi[a] + k];
        }
#pragma unroll
        for (int a = 0; a < 4; ++a) {
#pragma unroll
            for (int k = 0; k < 3; ++k)
                gx[3 * a + k] = coords[3 * xi[a] + k];
        }
#pragma unroll
        for (int a = 0; a < 4; ++a) {
            bool needy = (ti[a] == 2) | (ti[a] == 3);
            if (needy) {
#pragma unroll
                for (int k = 0; k < 3; ++k)
                    gy[3 * a + k] = coords[3 * yi[a] + k];
            } else {
#pragma unroll
                for (int k = 0; k < 3; ++k) gy[3 * a + k] = 0.0f;
            }
        }

        // streams: dipoles + quadrupoles (non-temporal)
        f32x4 dA = __builtin_nontemporal_load((const f32x4*)dip + 3 * g + 0);
        f32x4 dB = __builtin_nontemporal_load((const f32x4*)dip + 3 * g + 1);
        f32x4 dC = __builtin_nontemporal_load((const f32x4*)dip + 3 * g + 2);
        float dp[12] = {dA.x, dA.y, dA.z, dA.w, dB.x, dB.y, dB.z, dB.w,
                        dC.x, dC.y, dC.z, dC.w};

        float q[36];
#pragma unroll
        for (int k = 0; k < 9; ++k) {
            f32x4 v = __builtin_nontemporal_load((const f32x4*)quad + 9 * g + k);
            q[4 * k + 0] = v.x; q[4 * k + 1] = v.y;
            q[4 * k + 2] = v.z; q[4 * k + 3] = v.w;
        }

        float od[12], oq[36];
#pragma unroll
        for (int a = 0; a < 4; ++a) {
            float dz[3], dx[3], dy[3];
#pragma unroll
            for (int k = 0; k < 3; ++k) {
                dz[k] = gz[3 * a + k] - c[3 * a + k];
                dx[k] = gx[3 * a + k] - c[3 * a + k];
                dy[k] = gy[3 * a + k] - c[3 * a + k];
            }
            float R[9];
            rot_from_deltas(ti[a], dz, dx, dy, R);
            apply_rot(R, &dp[3 * a], &q[9 * a], &od[3 * a], &oq[9 * a]);
        }

        f32x4 odA = {od[0], od[1], od[2], od[3]};
        f32x4 odB = {od[4], od[5], od[6], od[7]};
        f32x4 odC = {od[8], od[9], od[10], od[11]};
        __builtin_nontemporal_store(odA, (f32x4*)out_d + 3 * g + 0);
        __builtin_nontemporal_store(odB, (f32x4*)out_d + 3 * g + 1);
        __builtin_nontemporal_store(odC, (f32x4*)out_d + 3 * g + 2);
#pragma unroll
        for (int k = 0; k < 9; ++k) {
            f32x4 v = {oq[4 * k + 0], oq[4 * k + 1], oq[4 * k + 2], oq[4 * k + 3]};
            __builtin_nontemporal_store(v, (f32x4*)out_q + 9 * g + k);
        }
    } else {
        // tail: scalar per-atom fallback
        for (int i = base; i < n; ++i) {
            int t = at[i];
            float cx = coords[3 * i + 0], cy = coords[3 * i + 1], cz = coords[3 * i + 2];
            int zi = za[i], xi = xa[i], yi = ya[i];
            float dz[3] = {coords[3 * zi + 0] - cx, coords[3 * zi + 1] - cy, coords[3 * zi + 2] - cz};
            float dx[3] = {coords[3 * xi + 0] - cx, coords[3 * xi + 1] - cy, coords[3 * xi + 2] - cz};
            float dy[3] = {coords[3 * yi + 0] - cx, coords[3 * yi + 1] - cy, coords[3 * yi + 2] - cz};
            float R[9];
            rot_from_deltas(t, dz, dx, dy, R);
            float dpl[3] = {dip[3 * i + 0], dip[3 * i + 1], dip[3 * i + 2]};
            float Q[9];
#pragma unroll
            for (int k = 0; k < 9; ++k) Q[k] = quad[9 * i + k];
            float od[3], oq[9];
            apply_rot(R, dpl, Q, od, oq);
#pragma unroll
            for (int k = 0; k < 3; ++k) out_d[3 * i + k] = od[k];
#pragma unroll
            for (int k = 0; k < 9; ++k) out_q[9 * i + k] = oq[k];
        }
    }
}

extern "C" void kernel_launch(void* const* d_in, const int* in_sizes, int n_in,
                              void* d_out, int out_size, void* d_ws, size_t ws_size,
                              hipStream_t stream) {
    const float* coords = (const float*)d_in[0];
    const int* za = (const int*)d_in[1];
    const int* xa = (const int*)d_in[2];
    const int* ya = (const int*)d_in[3];
    const int* at = (const int*)d_in[4];
    const float* dip = (const float*)d_in[5];
    const float* quad = (const float*)d_in[6];

    int n = in_sizes[1];  // z_atoms count == N
    float* out_d = (float*)d_out;
    float* out_q = out_d + (size_t)3 * n;

    int ngroups = (n + 3) / 4;
    int block = 256;
    int grid = (ngroups + block - 1) / block;
    mp_rot4_nt_kernel<<<grid, block, 0, stream>>>(coords, za, xa, ya, at, dip, quad,
                                                  out_d, out_q, ngroups, n);
}

// Round 5
// 408.757 us; speedup vs baseline: 1.0558x; 1.0558x over previous
//
#include <hip/hip_runtime.h>

// Two-pass split to keep the 48 MB coords array L3-resident for gathers:
//  pass 1: compute rotation frames (gathers) -> write x_vec,z_vec (24B/atom) to ws
//          working set = coords 48 + idx 64 + ws 96 = 208 MB < 256 MB L3
//  pass 2: pure streaming apply: R(96) + dip(48) + quad(144) -> d,q(192) @ ~HBM peak
// y_vec is reconstructed as cross(z,x) in pass 2 (exactly matches reference).
// NOTE: non-temporal loads/stores were tested and REGRESSED 2x on gfx950
// (partial-line no-allocate stores -> RMW amplification, WRITE 193->514 MB).

__device__ __forceinline__ float3 nrm3(float ax, float ay, float az) {
    float s = ax * ax + ay * ay + az * az;
    float r = 1.0f / sqrtf(s);
    return make_float3(ax * r, ay * r, az * r);
}

// Rotation rows from pre-gathered deltas. dz/dx/dy are (neighbor - self).
// Outputs only x row (R[0..2]) and z row (R[6..8]) are needed downstream.
__device__ __forceinline__ void rot_from_deltas(
    int t, const float* dz, const float* dx, const float* dy, float R[9])
{
    if (t == 5) {
        R[0] = 1.0f; R[1] = 0.0f; R[2] = 0.0f;
        R[6] = 0.0f; R[7] = 0.0f; R[8] = 1.0f;
        return;
    }

    float3 zv = nrm3(dz[0], dz[1], dz[2]);

    float3 xv;
    if (t == 4) {
        xv = make_float3(1.0f - zv.x, zv.x, 0.0f);
    } else {
        xv = nrm3(dx[0], dx[1], dx[2]);
    }

    if (t == 1) {
        zv = nrm3(zv.x + xv.x, zv.y + xv.y, zv.z + xv.z);
    }

    if (t == 2 || t == 3) {
        float3 yn = nrm3(dy[0], dy[1], dy[2]);
        if (t == 2) {
            xv = nrm3(xv.x + yn.x, xv.y + yn.y, xv.z + yn.z);
        } else {
            zv = nrm3(zv.x + xv.x + yn.x, zv.y + xv.y + yn.y, zv.z + xv.z + yn.z);
        }
    }

    float dzx = zv.x * xv.x + zv.y * xv.y + zv.z * xv.z;
    xv = nrm3(xv.x - zv.x * dzx, xv.y - zv.y * dzx, xv.z - zv.z * dzx);

    R[0] = xv.x; R[1] = xv.y; R[2] = xv.z;
    R[6] = zv.x; R[7] = zv.y; R[8] = zv.z;
}

// Full apply given x row + z row (y = cross(z,x)).
__device__ __forceinline__ void apply_rot_xz(
    const float xv[3], const float zv[3], const float dp[3], const float Q[9],
    float od[3], float oq[9])
{
    float R[9];
    R[0] = xv[0]; R[1] = xv[1]; R[2] = xv[2];
    R[3] = zv[1] * xv[2] - zv[2] * xv[1];
    R[4] = zv[2] * xv[0] - zv[0] * xv[2];
    R[5] = zv[0] * xv[1] - zv[1] * xv[0];
    R[6] = zv[0]; R[7] = zv[1]; R[8] = zv[2];

    od[0] = dp[0] * R[0] + dp[1] * R[3] + dp[2] * R[6];
    od[1] = dp[0] * R[1] + dp[1] * R[4] + dp[2] * R[7];
    od[2] = dp[0] * R[2] + dp[1] * R[5] + dp[2] * R[8];

    float M[9];
#pragma unroll
    for (int a = 0; a < 3; ++a)
#pragma unroll
        for (int l = 0; l < 3; ++l)
            M[a * 3 + l] = R[0 * 3 + a] * Q[0 * 3 + l]
                         + R[1 * 3 + a] * Q[1 * 3 + l]
                         + R[2 * 3 + a] * Q[2 * 3 + l];
#pragma unroll
    for (int a = 0; a < 3; ++a)
#pragma unroll
        for (int b = 0; b < 3; ++b)
            oq[a * 3 + b] = M[a * 3 + 0] * R[0 * 3 + b]
                          + M[a * 3 + 1] * R[1 * 3 + b]
                          + M[a * 3 + 2] * R[2 * 3 + b];
}

// ---------------- pass 1: frames -> ws (x_vec, z_vec per atom) ----------------
__global__ __launch_bounds__(256) void mp_pass1_rot(
    const float* __restrict__ coords,
    const int* __restrict__ za,
    const int* __restrict__ xa,
    const int* __restrict__ ya,
    const int* __restrict__ at,
    float* __restrict__ rws,          // 6 floats per atom: x0 x1 x2 z0 z1 z2
    int ngroups, int n)
{
    int g = blockIdx.x * blockDim.x + threadIdx.x;
    if (g >= ngroups) return;
    int base = 4 * g;

    if (base + 4 <= n) {
        int4 z4 = ((const int4*)za)[g];
        int4 x4 = ((const int4*)xa)[g];
        int4 y4 = ((const int4*)ya)[g];
        int4 t4 = ((const int4*)at)[g];
        int zi[4] = {z4.x, z4.y, z4.z, z4.w};
        int xi[4] = {x4.x, x4.y, x4.z, x4.w};
        int yi[4] = {y4.x, y4.y, y4.z, y4.w};
        int ti[4] = {t4.x, t4.y, t4.z, t4.w};

        float4 cA = ((const float4*)coords)[3 * g + 0];
        float4 cB = ((const float4*)coords)[3 * g + 1];
        float4 cC = ((const float4*)coords)[3 * g + 2];
        float c[12] = {cA.x, cA.y, cA.z, cA.w, cB.x, cB.y, cB.z, cB.w,
                       cC.x, cC.y, cC.z, cC.w};

        // hoisted gathers (L3-resident coords)
        float gz[12], gx[12], gy[12];
#pragma unroll
        for (int a = 0; a < 4; ++a)
#pragma unroll
            for (int k = 0; k < 3; ++k)
                gz[3 * a + k] = coords[3 * zi[a] + k];
#pragma unroll
        for (int a = 0; a < 4; ++a)
#pragma unroll
            for (int k = 0; k < 3; ++k)
                gx[3 * a + k] = coords[3 * xi[a] + k];
#pragma unroll
        for (int a = 0; a < 4; ++a) {
            bool needy = (ti[a] == 2) | (ti[a] == 3);
            if (needy) {
#pragma unroll
                for (int k = 0; k < 3; ++k)
                    gy[3 * a + k] = coords[3 * yi[a] + k];
            } else {
#pragma unroll
                for (int k = 0; k < 3; ++k) gy[3 * a + k] = 0.0f;
            }
        }

        float rz[24];
#pragma unroll
        for (int a = 0; a < 4; ++a) {
            float dz[3], dx[3], dy[3];
#pragma unroll
            for (int k = 0; k < 3; ++k) {
                dz[k] = gz[3 * a + k] - c[3 * a + k];
                dx[k] = gx[3 * a + k] - c[3 * a + k];
                dy[k] = gy[3 * a + k] - c[3 * a + k];
            }
            float R[9];
            rot_from_deltas(ti[a], dz, dx, dy, R);
            rz[6 * a + 0] = R[0]; rz[6 * a + 1] = R[1]; rz[6 * a + 2] = R[2];
            rz[6 * a + 3] = R[6]; rz[6 * a + 4] = R[7]; rz[6 * a + 5] = R[8];
        }

#pragma unroll
        for (int k = 0; k < 6; ++k)
            ((float4*)rws)[6 * g + k] = make_float4(rz[4 * k + 0], rz[4 * k + 1],
                                                   rz[4 * k + 2], rz[4 * k + 3]);
    } else {
        for (int i = base; i < n; ++i) {
            int t = at[i];
            float cx = coords[3 * i + 0], cy = coords[3 * i + 1], cz = coords[3 * i + 2];
            int zi = za[i], xi = xa[i], yi = ya[i];
            float dz[3] = {coords[3 * zi + 0] - cx, coords[3 * zi + 1] - cy, coords[3 * zi + 2] - cz};
            float dx[3] = {coords[3 * xi + 0] - cx, coords[3 * xi + 1] - cy, coords[3 * xi + 2] - cz};
            float dy[3] = {coords[3 * yi + 0] - cx, coords[3 * yi + 1] - cy, coords[3 * yi + 2] - cz};
            float R[9];
            rot_from_deltas(t, dz, dx, dy, R);
            rws[6 * i + 0] = R[0]; rws[6 * i + 1] = R[1]; rws[6 * i + 2] = R[2];
            rws[6 * i + 3] = R[6]; rws[6 * i + 4] = R[7]; rws[6 * i + 5] = R[8];
        }
    }
}

// ---------------- pass 2: streaming apply ----------------
__global__ __launch_bounds__(256) void mp_pass2_apply(
    const float* __restrict__ rws,
    const float* __restrict__ dip,
    const float* __restrict__ quad,
    float* __restrict__ out_d,
    float* __restrict__ out_q,
    int ngroups, int n)
{
    int g = blockIdx.x * blockDim.x + threadIdx.x;
    if (g >= ngroups) return;
    int base = 4 * g;

    if (base + 4 <= n) {
        float rz[24];
#pragma unroll
        for (int k = 0; k < 6; ++k) {
            float4 v = ((const float4*)rws)[6 * g + k];
            rz[4 * k + 0] = v.x; rz[4 * k + 1] = v.y;
            rz[4 * k + 2] = v.z; rz[4 * k + 3] = v.w;
        }

        float4 dA = ((const float4*)dip)[3 * g + 0];
        float4 dB = ((const float4*)dip)[3 * g + 1];
        float4 dC = ((const float4*)dip)[3 * g + 2];
        float dp[12] = {dA.x, dA.y, dA.z, dA.w, dB.x, dB.y, dB.z, dB.w,
                        dC.x, dC.y, dC.z, dC.w};

        float q[36];
#pragma unroll
        for (int k = 0; k < 9; ++k) {
            float4 v = ((const float4*)quad)[9 * g + k];
            q[4 * k + 0] = v.x; q[4 * k + 1] = v.y;
            q[4 * k + 2] = v.z; q[4 * k + 3] = v.w;
        }

        float od[12], oq[36];
#pragma unroll
        for (int a = 0; a < 4; ++a) {
            apply_rot_xz(&rz[6 * a + 0], &rz[6 * a + 3],
                         &dp[3 * a], &q[9 * a], &od[3 * a], &oq[9 * a]);
        }

        ((float4*)out_d)[3 * g + 0] = make_float4(od[0], od[1], od[2], od[3]);
        ((float4*)out_d)[3 * g + 1] = make_float4(od[4], od[5], od[6], od[7]);
        ((float4*)out_d)[3 * g + 2] = make_float4(od[8], od[9], od[10], od[11]);
#pragma unroll
        for (int k = 0; k < 9; ++k)
            ((float4*)out_q)[9 * g + k] = make_float4(oq[4 * k + 0], oq[4 * k + 1],
                                                      oq[4 * k + 2], oq[4 * k + 3]);
    } else {
        for (int i = base; i < n; ++i) {
            float xv[3] = {rws[6 * i + 0], rws[6 * i + 1], rws[6 * i + 2]};
            float zv[3] = {rws[6 * i + 3], rws[6 * i + 4], rws[6 * i + 5]};
            float dpl[3] = {dip[3 * i + 0], dip[3 * i + 1], dip[3 * i + 2]};
            float Q[9];
#pragma unroll
            for (int k = 0; k < 9; ++k) Q[k] = quad[9 * i + k];
            float od[3], oq[9];
            apply_rot_xz(xv, zv, dpl, Q, od, oq);
#pragma unroll
            for (int k = 0; k < 3; ++k) out_d[3 * i + k] = od[k];
#pragma unroll
            for (int k = 0; k < 9; ++k) out_q[9 * i + k] = oq[k];
        }
    }
}

// ---------------- fallback: fused single-pass (R2 kernel) ----------------
__global__ __launch_bounds__(256) void mp_fused_kernel(
    const float* __restrict__ coords,
    const int* __restrict__ za,
    const int* __restrict__ xa,
    const int* __restrict__ ya,
    const int* __restrict__ at,
    const float* __restrict__ dip,
    const float* __restrict__ quad,
    float* __restrict__ out_d,
    float* __restrict__ out_q,
    int n)
{
    int i = blockIdx.x * blockDim.x + threadIdx.x;
    if (i >= n) return;
    int t = at[i];
    float cx = coords[3 * i + 0], cy = coords[3 * i + 1], cz = coords[3 * i + 2];
    int zi = za[i], xi = xa[i], yi = ya[i];
    float dz[3] = {coords[3 * zi + 0] - cx, coords[3 * zi + 1] - cy, coords[3 * zi + 2] - cz};
    float dx[3] = {coords[3 * xi + 0] - cx, coords[3 * xi + 1] - cy, coords[3 * xi + 2] - cz};
    float dy[3];
    if (t == 2 || t == 3) {
        dy[0] = coords[3 * yi + 0] - cx; dy[1] = coords[3 * yi + 1] - cy; dy[2] = coords[3 * yi + 2] - cz;
    } else { dy[0] = dy[1] = dy[2] = 0.0f; }
    float R[9];
    rot_from_deltas(t, dz, dx, dy, R);
    float xv[3] = {R[0], R[1], R[2]}, zv[3] = {R[6], R[7], R[8]};
    float dpl[3] = {dip[3 * i + 0], dip[3 * i + 1], dip[3 * i + 2]};
    float Q[9];
#pragma unroll
    for (int k = 0; k < 9; ++k) Q[k] = quad[9 * i + k];
    float od[3], oq[9];
    apply_rot_xz(xv, zv, dpl, Q, od, oq);
#pragma unroll
    for (int k = 0; k < 3; ++k) out_d[3 * i + k] = od[k];
#pragma unroll
    for (int k = 0; k < 9; ++k) out_q[9 * i + k] = oq[k];
}

extern "C" void kernel_launch(void* const* d_in, const int* in_sizes, int n_in,
                              void* d_out, int out_size, void* d_ws, size_t ws_size,
                              hipStream_t stream) {
    const float* coords = (const float*)d_in[0];
    const int* za = (const int*)d_in[1];
    const int* xa = (const int*)d_in[2];
    const int* ya = (const int*)d_in[3];
    const int* at = (const int*)d_in[4];
    const float* dip = (const float*)d_in[5];
    const float* quad = (const float*)d_in[6];

    int n = in_sizes[1];  // z_atoms count == N
    float* out_d = (float*)d_out;
    float* out_q = out_d + (size_t)3 * n;

    int ngroups = (n + 3) / 4;
    int block = 256;
    int grid = (ngroups + block - 1) / block;

    size_t need = (size_t)n * 6 * sizeof(float);
    if (ws_size >= need) {
        float* rws = (float*)d_ws;
        mp_pass1_rot<<<grid, block, 0, stream>>>(coords, za, xa, ya, at, rws,
                                                 ngroups, n);
        mp_pass2_apply<<<grid, block, 0, stream>>>(rws, dip, quad, out_d, out_q,
                                                   ngroups, n);
    } else {
        int grid1 = (n + block - 1) / block;
        mp_fused_kernel<<<grid1, block, 0, stream>>>(coords, za, xa, ya, at,
                                                     dip, quad, out_d, out_q, n);
    }
}

// Round 6
// 223.439 us; speedup vs baseline: 1.9315x; 1.8294x over previous
//
#include <hip/hip_runtime.h>

// Fused single pass, 4 atoms/thread (float4 sequential I/O), with gathers
// PREDICATED on exact axis_type need:
//   z gather: t != 5      (5/6 of atoms)
//   x gather: t <= 3      (4/6 of atoms)
//   y gather: t == 2 || 3 (2/6 of atoms)
// Random 64B-line gather traffic is the measured bottleneck (~3 TB/s
// effective); skipping unneeded gathers cuts it ~21%.
// REJECTED by measurement: non-temporal ld/st (2x regression, partial-line
// RMW), two-pass split via ws (pass2 streams at only 2.4 TB/s + 96MB scratch
// round trip, and gather misses did NOT improve).

__device__ __forceinline__ float3 nrm3(float ax, float ay, float az) {
    float s = ax * ax + ay * ay + az * az;
    float r = 1.0f / sqrtf(s);
    return make_float3(ax * r, ay * r, az * r);
}

// Rotation x row (R[0..2]) and z row (R[6..8]) from pre-gathered deltas.
__device__ __forceinline__ void rot_from_deltas(
    int t, const float* dz, const float* dx, const float* dy, float R[9])
{
    if (t == 5) {
        R[0] = 1.0f; R[1] = 0.0f; R[2] = 0.0f;
        R[6] = 0.0f; R[7] = 0.0f; R[8] = 1.0f;
        return;
    }

    float3 zv = nrm3(dz[0], dz[1], dz[2]);

    float3 xv;
    if (t == 4) {
        xv = make_float3(1.0f - zv.x, zv.x, 0.0f);
    } else {
        xv = nrm3(dx[0], dx[1], dx[2]);
    }

    if (t == 1) {
        zv = nrm3(zv.x + xv.x, zv.y + xv.y, zv.z + xv.z);
    }

    if (t == 2 || t == 3) {
        float3 yn = nrm3(dy[0], dy[1], dy[2]);
        if (t == 2) {
            xv = nrm3(xv.x + yn.x, xv.y + yn.y, xv.z + yn.z);
        } else {
            zv = nrm3(zv.x + xv.x + yn.x, zv.y + xv.y + yn.y, zv.z + xv.z + yn.z);
        }
    }

    float dzx = zv.x * xv.x + zv.y * xv.y + zv.z * xv.z;
    xv = nrm3(xv.x - zv.x * dzx, xv.y - zv.y * dzx, xv.z - zv.z * dzx);

    R[0] = xv.x; R[1] = xv.y; R[2] = xv.z;
    R[6] = zv.x; R[7] = zv.y; R[8] = zv.z;
}

// Full apply given x row + z row (y = cross(z,x)).
__device__ __forceinline__ void apply_rot_xz(
    const float xv[3], const float zv[3], const float dp[3], const float Q[9],
    float od[3], float oq[9])
{
    float R[9];
    R[0] = xv[0]; R[1] = xv[1]; R[2] = xv[2];
    R[3] = zv[1] * xv[2] - zv[2] * xv[1];
    R[4] = zv[2] * xv[0] - zv[0] * xv[2];
    R[5] = zv[0] * xv[1] - zv[1] * xv[0];
    R[6] = zv[0]; R[7] = zv[1]; R[8] = zv[2];

    od[0] = dp[0] * R[0] + dp[1] * R[3] + dp[2] * R[6];
    od[1] = dp[0] * R[1] + dp[1] * R[4] + dp[2] * R[7];
    od[2] = dp[0] * R[2] + dp[1] * R[5] + dp[2] * R[8];

    float M[9];
#pragma unroll
    for (int a = 0; a < 3; ++a)
#pragma unroll
        for (int l = 0; l < 3; ++l)
            M[a * 3 + l] = R[0 * 3 + a] * Q[0 * 3 + l]
                         + R[1 * 3 + a] * Q[1 * 3 + l]
                         + R[2 * 3 + a] * Q[2 * 3 + l];
#pragma unroll
    for (int a = 0; a < 3; ++a)
#pragma unroll
        for (int b = 0; b < 3; ++b)
            oq[a * 3 + b] = M[a * 3 + 0] * R[0 * 3 + b]
                          + M[a * 3 + 1] * R[1 * 3 + b]
                          + M[a * 3 + 2] * R[2 * 3 + b];
}

__global__ __launch_bounds__(256) void mp_rot4_pred_kernel(
    const float* __restrict__ coords,
    const int* __restrict__ za,
    const int* __restrict__ xa,
    const int* __restrict__ ya,
    const int* __restrict__ at,
    const float* __restrict__ dip,
    const float* __restrict__ quad,
    float* __restrict__ out_d,
    float* __restrict__ out_q,
    int ngroups, int n)
{
    int g = blockIdx.x * blockDim.x + threadIdx.x;
    if (g >= ngroups) return;
    int base = 4 * g;

    if (base + 4 <= n) {
        int4 z4 = ((const int4*)za)[g];
        int4 x4 = ((const int4*)xa)[g];
        int4 y4 = ((const int4*)ya)[g];
        int4 t4 = ((const int4*)at)[g];
        int zi[4] = {z4.x, z4.y, z4.z, z4.w};
        int xi[4] = {x4.x, x4.y, x4.z, x4.w};
        int yi[4] = {y4.x, y4.y, y4.z, y4.w};
        int ti[4] = {t4.x, t4.y, t4.z, t4.w};

        float4 cA = ((const float4*)coords)[3 * g + 0];
        float4 cB = ((const float4*)coords)[3 * g + 1];
        float4 cC = ((const float4*)coords)[3 * g + 2];
        float c[12] = {cA.x, cA.y, cA.z, cA.w, cB.x, cB.y, cB.z, cB.w,
                       cC.x, cC.y, cC.z, cC.w};

        // ---- hoisted, PREDICATED gathers (issue all before any math) ----
        float gz[12], gx[12], gy[12];
#pragma unroll
        for (int a = 0; a < 4; ++a) {
            if (ti[a] != 5) {
#pragma unroll
                for (int k = 0; k < 3; ++k)
                    gz[3 * a + k] = coords[3 * zi[a] + k];
            } else {
                gz[3 * a + 0] = 1.0f; gz[3 * a + 1] = 0.0f; gz[3 * a + 2] = 0.0f;
            }
        }
#pragma unroll
        for (int a = 0; a < 4; ++a) {
            if (ti[a] <= 3) {
#pragma unroll
                for (int k = 0; k < 3; ++k)
                    gx[3 * a + k] = coords[3 * xi[a] + k];
            } else {
                gx[3 * a + 0] = 1.0f; gx[3 * a + 1] = 0.0f; gx[3 * a + 2] = 0.0f;
            }
        }
#pragma unroll
        for (int a = 0; a < 4; ++a) {
            if ((ti[a] == 2) | (ti[a] == 3)) {
#pragma unroll
                for (int k = 0; k < 3; ++k)
                    gy[3 * a + k] = coords[3 * yi[a] + k];
            } else {
                gy[3 * a + 0] = 1.0f; gy[3 * a + 1] = 0.0f; gy[3 * a + 2] = 0.0f;
            }
        }

        // sequential streams
        float4 dA = ((const float4*)dip)[3 * g + 0];
        float4 dB = ((const float4*)dip)[3 * g + 1];
        float4 dC = ((const float4*)dip)[3 * g + 2];
        float dp[12] = {dA.x, dA.y, dA.z, dA.w, dB.x, dB.y, dB.z, dB.w,
                        dC.x, dC.y, dC.z, dC.w};

        float q[36];
#pragma unroll
        for (int k = 0; k < 9; ++k) {
            float4 v = ((const float4*)quad)[9 * g + k];
            q[4 * k + 0] = v.x; q[4 * k + 1] = v.y;
            q[4 * k + 2] = v.z; q[4 * k + 3] = v.w;
        }

        float od[12], oq[36];
#pragma unroll
        for (int a = 0; a < 4; ++a) {
            float dz[3], dx[3], dy[3];
            bool needz = ti[a] != 5;
            bool needx = ti[a] <= 3;
            bool needy = (ti[a] == 2) | (ti[a] == 3);
#pragma unroll
            for (int k = 0; k < 3; ++k) {
                dz[k] = needz ? (gz[3 * a + k] - c[3 * a + k]) : gz[3 * a + k];
                dx[k] = needx ? (gx[3 * a + k] - c[3 * a + k]) : gx[3 * a + k];
                dy[k] = needy ? (gy[3 * a + k] - c[3 * a + k]) : gy[3 * a + k];
            }
            float R[9];
            rot_from_deltas(ti[a], dz, dx, dy, R);
            apply_rot_xz(&R[0], &R[6], &dp[3 * a], &q[9 * a],
                         &od[3 * a], &oq[9 * a]);
        }

        ((float4*)out_d)[3 * g + 0] = make_float4(od[0], od[1], od[2], od[3]);
        ((float4*)out_d)[3 * g + 1] = make_float4(od[4], od[5], od[6], od[7]);
        ((float4*)out_d)[3 * g + 2] = make_float4(od[8], od[9], od[10], od[11]);
#pragma unroll
        for (int k = 0; k < 9; ++k)
            ((float4*)out_q)[9 * g + k] = make_float4(oq[4 * k + 0], oq[4 * k + 1],
                                                      oq[4 * k + 2], oq[4 * k + 3]);
    } else {
        // tail: scalar per-atom fallback
        for (int i = base; i < n; ++i) {
            int t = at[i];
            float cx = coords[3 * i + 0], cy = coords[3 * i + 1], cz = coords[3 * i + 2];
            int zi = za[i], xi = xa[i], yi = ya[i];
            float dz[3] = {1.0f, 0.0f, 0.0f};
            float dx[3] = {1.0f, 0.0f, 0.0f};
            float dy[3] = {1.0f, 0.0f, 0.0f};
            if (t != 5) {
                dz[0] = coords[3 * zi + 0] - cx; dz[1] = coords[3 * zi + 1] - cy; dz[2] = coords[3 * zi + 2] - cz;
            }
            if (t <= 3) {
                dx[0] = coords[3 * xi + 0] - cx; dx[1] = coords[3 * xi + 1] - cy; dx[2] = coords[3 * xi + 2] - cz;
            }
            if (t == 2 || t == 3) {
                dy[0] = coords[3 * yi + 0] - cx; dy[1] = coords[3 * yi + 1] - cy; dy[2] = coords[3 * yi + 2] - cz;
            }
            float R[9];
            rot_from_deltas(t, dz, dx, dy, R);
            float dpl[3] = {dip[3 * i + 0], dip[3 * i + 1], dip[3 * i + 2]};
            float Q[9];
#pragma unroll
            for (int k = 0; k < 9; ++k) Q[k] = quad[9 * i + k];
            float od[3], oq[9];
            apply_rot_xz(&R[0], &R[6], dpl, Q, od, oq);
#pragma unroll
            for (int k = 0; k < 3; ++k) out_d[3 * i + k] = od[k];
#pragma unroll
            for (int k = 0; k < 9; ++k) out_q[9 * i + k] = oq[k];
        }
    }
}

extern "C" void kernel_launch(void* const* d_in, const int* in_sizes, int n_in,
                              void* d_out, int out_size, void* d_ws, size_t ws_size,
                              hipStream_t stream) {
    const float* coords = (const float*)d_in[0];
    const int* za = (const int*)d_in[1];
    const int* xa = (const int*)d_in[2];
    const int* ya = (const int*)d_in[3];
    const int* at = (const int*)d_in[4];
    const float* dip = (const float*)d_in[5];
    const float* quad = (const float*)d_in[6];

    int n = in_sizes[1];  // z_atoms count == N
    float* out_d = (float*)d_out;
    float* out_q = out_d + (size_t)3 * n;

    int ngroups = (n + 3) / 4;
    int block = 256;
    int grid = (ngroups + block - 1) / block;
    mp_rot4_pred_kernel<<<grid, block, 0, stream>>>(coords, za, xa, ya, at,
                                                    dip, quad, out_d, out_q,
                                                    ngroups, n);
}